// Round 1
// baseline (561.058 us; speedup 1.0000x reference)
//
#include <hip/hip_runtime.h>
#include <hip/hip_bf16.h>
#include <cstdint>

// ---------------- workspace layout (float offsets) ----------------
#define N_A1   (16384ull*1152ull)          // conv1 out [B][32][36]
#define N_A2   (16384ull*256ull)           // pooled    [B][256]
#define OFF_A1   0ull
#define OFF_A2   (OFF_A1 + N_A1)
#define OFF_W1T  (OFF_A2 + N_A2)           // fc1_w^T  [256][128]
#define OFF_W2T  (OFF_W1T + 32768ull)      // fc2_w^T  [135][64]
#define OFF_R1T  (OFF_W2T + 8640ull)       // row1^T [64][32]
#define OFF_R2T  (OFF_R1T + 2048ull)       // row2^T [32][16]
#define OFF_R3T  (OFF_R2T + 512ull)        // row3^T [16][10]
#define OFF_C1T  (OFF_R3T + 160ull)
#define OFF_C2T  (OFF_C1T + 2048ull)
#define OFF_C3T  (OFF_C2T + 512ull)
#define OFF_H1T  (OFF_C3T + 160ull)
#define OFF_H2T  (OFF_H1T + 2048ull)
#define OFF_H3T  (OFF_H2T + 512ull)        // hand3^T [16][7]

// ---------------- prep: transpose all FC/head weights ----------------
__global__ __launch_bounds__(256) void k_prep(
    const float* __restrict__ f1w, const float* __restrict__ f2w,
    const float* __restrict__ r1, const float* __restrict__ r2, const float* __restrict__ r3,
    const float* __restrict__ c1, const float* __restrict__ c2, const float* __restrict__ c3,
    const float* __restrict__ h1, const float* __restrict__ h2, const float* __restrict__ h3,
    float* __restrict__ ws) {
  const float* srcs[11] = {f1w, f2w, r1, r2, r3, c1, c2, c3, h1, h2, h3};
  float* dsts[11] = {ws+OFF_W1T, ws+OFF_W2T, ws+OFF_R1T, ws+OFF_R2T, ws+OFF_R3T,
                     ws+OFF_C1T, ws+OFF_C2T, ws+OFF_C3T, ws+OFF_H1T, ws+OFF_H2T, ws+OFF_H3T};
  const int Rs[11] = {128, 64, 32, 16, 10, 32, 16, 10, 32, 16, 7};
  const int Cs[11] = {256, 135, 64, 32, 16, 64, 32, 16, 64, 32, 16};
  for (int seg = 0; seg < 11; ++seg) {
    int n = Rs[seg] * Cs[seg];
    for (int i = blockIdx.x * blockDim.x + threadIdx.x; i < n; i += gridDim.x * blockDim.x) {
      int r = i / Cs[seg];
      int c = i - r * Cs[seg];
      dsts[seg][c * Rs[seg] + r] = srcs[seg][i];   // dst[k][j] = src[j][k]
    }
  }
}

// ---------------- conv1: [B,9,10,10] -> relu -> [B,32,6,6] ----------------
// block = 256 threads = 8 samples x 32 oc. Input plane per-ic held in registers.
__global__ __launch_bounds__(256) void k_conv1(
    const float* __restrict__ board, const float* __restrict__ w,
    const float* __restrict__ bias_g, float* __restrict__ a1) {
  __shared__ float wl[225 * 32];     // [k][oc]
  __shared__ float inl[8 * 900];     // 8 samples
  const int tid = threadIdx.x;
  for (int i = tid; i < 7200; i += 256) {
    int oc = i / 225, k = i - oc * 225;
    wl[k * 32 + oc] = w[i];
  }
  size_t base = (size_t)blockIdx.x * 8ull * 900ull;
  for (int i = tid; i < 7200; i += 256) inl[i] = board[base + i];
  __syncthreads();

  const int oc = tid & 31, ss = tid >> 5;
  float acc[36];
  {
    float bv = bias_g[oc];
#pragma unroll
    for (int p = 0; p < 36; ++p) acc[p] = bv;
  }
#pragma unroll 1
  for (int ic = 0; ic < 9; ++ic) {
    float plane[100];
    const float4* p4 = reinterpret_cast<const float4*>(&inl[ss * 900 + ic * 100]);
#pragma unroll
    for (int q = 0; q < 25; ++q) {
      float4 v = p4[q];
      plane[4*q] = v.x; plane[4*q+1] = v.y; plane[4*q+2] = v.z; plane[4*q+3] = v.w;
    }
    const float* wk = &wl[ic * 25 * 32 + oc];
#pragma unroll
    for (int ky = 0; ky < 5; ++ky) {
#pragma unroll
      for (int kx = 0; kx < 5; ++kx) {
        float wv = wk[(ky * 5 + kx) * 32];
#pragma unroll
        for (int r = 0; r < 6; ++r) {
#pragma unroll
          for (int c = 0; c < 6; ++c) {
            acc[r * 6 + c] = fmaf(wv, plane[(r + ky) * 10 + c + kx], acc[r * 6 + c]);
          }
        }
      }
    }
  }
  size_t s = (size_t)blockIdx.x * 8ull + (size_t)ss;
  float4* out4 = reinterpret_cast<float4*>(&a1[s * 1152ull + (size_t)oc * 36ull]);
#pragma unroll
  for (int q = 0; q < 9; ++q) {
    float4 v;
    v.x = fmaxf(acc[4*q], 0.f);   v.y = fmaxf(acc[4*q+1], 0.f);
    v.z = fmaxf(acc[4*q+2], 0.f); v.w = fmaxf(acc[4*q+3], 0.f);
    out4[q] = v;
  }
}

// -------- conv2 + relu + 2x2 maxpool: [B,32,6,6] -> [B,256] --------
// block = 512 threads = 8 samples x 64 oc
__global__ __launch_bounds__(512) void k_conv2(
    const float* __restrict__ a1, const float* __restrict__ w,
    const float* __restrict__ bias_g, float* __restrict__ a2) {
  __shared__ float wl[288 * 64];     // [k][oc]  73.7 KB
  __shared__ float inl[8 * 1152];    // 36.9 KB
  const int tid = threadIdx.x;
  for (int i = tid; i < 18432; i += 512) {
    int oc = i / 288, k = i - oc * 288;
    wl[k * 64 + oc] = w[i];
  }
  size_t base = (size_t)blockIdx.x * 8ull * 1152ull;
  for (int i = tid; i < 9216; i += 512) inl[i] = a1[base + i];
  __syncthreads();

  const int oc = tid & 63, ss = tid >> 6;
  float acc[16];
  {
    float bv = bias_g[oc];
#pragma unroll
    for (int p = 0; p < 16; ++p) acc[p] = bv;
  }
#pragma unroll 1
  for (int ic = 0; ic < 32; ++ic) {
    float plane[36];
    const float4* p4 = reinterpret_cast<const float4*>(&inl[ss * 1152 + ic * 36]);
#pragma unroll
    for (int q = 0; q < 9; ++q) {
      float4 v = p4[q];
      plane[4*q] = v.x; plane[4*q+1] = v.y; plane[4*q+2] = v.z; plane[4*q+3] = v.w;
    }
    const float* wk = &wl[ic * 9 * 64 + oc];
#pragma unroll
    for (int ky = 0; ky < 3; ++ky) {
#pragma unroll
      for (int kx = 0; kx < 3; ++kx) {
        float wv = wk[(ky * 3 + kx) * 64];
#pragma unroll
        for (int y = 0; y < 4; ++y) {
#pragma unroll
          for (int x = 0; x < 4; ++x) {
            acc[y * 4 + x] = fmaf(wv, plane[(y + ky) * 6 + x + kx], acc[y * 4 + x]);
          }
        }
      }
    }
  }
  size_t s = (size_t)blockIdx.x * 8ull + (size_t)ss;
  float4 v;
  v.x = fmaxf(fmaxf(acc[0],  acc[1]),  fmaxf(acc[4],  acc[5]));
  v.y = fmaxf(fmaxf(acc[2],  acc[3]),  fmaxf(acc[6],  acc[7]));
  v.z = fmaxf(fmaxf(acc[8],  acc[9]),  fmaxf(acc[12], acc[13]));
  v.w = fmaxf(fmaxf(acc[10], acc[11]), fmaxf(acc[14], acc[15]));
  v.x = fmaxf(v.x, 0.f); v.y = fmaxf(v.y, 0.f); v.z = fmaxf(v.z, 0.f); v.w = fmaxf(v.w, 0.f);
  *reinterpret_cast<float4*>(&a2[s * 256ull + (size_t)oc * 4ull]) = v;
}

// -------- fc1 -> concat -> fc2 -> 3 heads -> outer product --------
// block = 256 threads, 64 samples. lane = sample, wave group = output tile.
__global__ __launch_bounds__(256) void k_fc(
    const float* __restrict__ a2, const float* __restrict__ card,
    const float* __restrict__ ws,
    const float* __restrict__ f1b, const float* __restrict__ f2b,
    const float* __restrict__ rb1, const float* __restrict__ rb2, const float* __restrict__ rb3,
    const float* __restrict__ cb1, const float* __restrict__ cb2, const float* __restrict__ cb3,
    const float* __restrict__ hb1g, const float* __restrict__ hb2g, const float* __restrict__ hb3g,
    float* __restrict__ out) {
  __shared__ float xb[64 * 257];     // pitch 257 -> conflict-free column reads
  __shared__ float cbuf[64 * 8];
  __shared__ float h1s[64 * 129];
  __shared__ float h2s[64 * 65];
  __shared__ float ro[64 * 12];
  __shared__ float co[64 * 12];
  __shared__ float ha[64 * 8];
  const int tid = threadIdx.x;
  const int s0 = blockIdx.x * 64;

  for (int i = tid; i < 64 * 256; i += 256) {
    int s_ = i >> 8, k_ = i & 255;
    xb[s_ * 257 + k_] = a2[(size_t)(s0 + s_) * 256ull + k_];
  }
  for (int i = tid; i < 64 * 7; i += 256) {
    int s_ = i / 7, k_ = i - s_ * 7;
    cbuf[s_ * 8 + k_] = card[(size_t)(s0 + s_) * 7ull + k_];
  }
  __syncthreads();

  const int s = tid & 63;
  const int grp = __builtin_amdgcn_readfirstlane(tid >> 6);
  const float* w1t = ws + OFF_W1T;
  const float* w2t = ws + OFF_W2T;

  // ---- fc1: 256 -> 128, relu ----
  {
    const int j0 = grp * 32;
    float acc[32];
#pragma unroll
    for (int j = 0; j < 32; ++j) acc[j] = f1b[j0 + j];
    for (int k = 0; k < 256; ++k) {
      float xk = xb[s * 257 + k];
      const float* wr = w1t + k * 128 + j0;
#pragma unroll
      for (int j = 0; j < 32; ++j) acc[j] = fmaf(xk, wr[j], acc[j]);
    }
#pragma unroll
    for (int j = 0; j < 32; ++j) h1s[s * 129 + j0 + j] = fmaxf(acc[j], 0.f);
  }
  __syncthreads();

  // ---- fc2: 135 -> 64, relu ----
  {
    const int m0 = grp * 16;
    float acc[16];
#pragma unroll
    for (int m = 0; m < 16; ++m) acc[m] = f2b[m0 + m];
    for (int k = 0; k < 128; ++k) {
      float hk = h1s[s * 129 + k];
      const float* wr = w2t + k * 64 + m0;
#pragma unroll
      for (int m = 0; m < 16; ++m) acc[m] = fmaf(hk, wr[m], acc[m]);
    }
#pragma unroll
    for (int k = 0; k < 7; ++k) {
      float hk = cbuf[s * 8 + k];
      const float* wr = w2t + (128 + k) * 64 + m0;
#pragma unroll
      for (int m = 0; m < 16; ++m) acc[m] = fmaf(hk, wr[m], acc[m]);
    }
#pragma unroll
    for (int m = 0; m < 16; ++m) h2s[s * 65 + m0 + m] = fmaxf(acc[m], 0.f);
  }
  __syncthreads();

  // ---- heads (wave 0: row, 1: col, 2: hand; wave 3 idle) ----
  if (grp < 3) {
    const float* hw1 = (grp == 0) ? ws + OFF_R1T : (grp == 1) ? ws + OFF_C1T : ws + OFF_H1T;
    const float* hw2 = (grp == 0) ? ws + OFF_R2T : (grp == 1) ? ws + OFF_C2T : ws + OFF_H2T;
    const float* hw3 = (grp == 0) ? ws + OFF_R3T : (grp == 1) ? ws + OFF_C3T : ws + OFF_H3T;
    const float* b1 = (grp == 0) ? rb1 : (grp == 1) ? cb1 : hb1g;
    const float* b2 = (grp == 0) ? rb2 : (grp == 1) ? cb2 : hb2g;
    const float* b3 = (grp == 0) ? rb3 : (grp == 1) ? cb3 : hb3g;

    float g1[32];
#pragma unroll
    for (int j = 0; j < 32; ++j) g1[j] = b1[j];
    for (int k = 0; k < 64; ++k) {
      float hk = h2s[s * 65 + k];
      const float* wr = hw1 + k * 32;
#pragma unroll
      for (int j = 0; j < 32; ++j) g1[j] = fmaf(hk, wr[j], g1[j]);
    }
    float g2[16];
#pragma unroll
    for (int m = 0; m < 16; ++m) g2[m] = b2[m];
#pragma unroll
    for (int k = 0; k < 32; ++k) {
      const float* wr = hw2 + k * 16;
#pragma unroll
      for (int m = 0; m < 16; ++m) g2[m] = fmaf(g1[k], wr[m], g2[m]);
    }
    if (grp == 2) {
      float g3[7];
#pragma unroll
      for (int m = 0; m < 7; ++m) g3[m] = b3[m];
#pragma unroll
      for (int k = 0; k < 16; ++k) {
        const float* wr = hw3 + k * 7;
#pragma unroll
        for (int m = 0; m < 7; ++m) g3[m] = fmaf(g2[k], wr[m], g3[m]);
      }
#pragma unroll
      for (int m = 0; m < 7; ++m) ha[s * 8 + m] = g3[m];
    } else {
      float g3[10];
#pragma unroll
      for (int m = 0; m < 10; ++m) g3[m] = b3[m];
#pragma unroll
      for (int k = 0; k < 16; ++k) {
        const float* wr = hw3 + k * 10;
#pragma unroll
        for (int m = 0; m < 10; ++m) g3[m] = fmaf(g2[k], wr[m], g3[m]);
      }
      float* dst = (grp == 0) ? ro : co;
#pragma unroll
      for (int m = 0; m < 10; ++m) dst[s * 12 + m] = g3[m];
    }
  }
  __syncthreads();

  // ---- outer product: out[s][h*100 + r*10 + c] ----
  for (int idx = tid; idx < 64 * 700; idx += 256) {
    int s_ = idx / 700;
    int q = idx - s_ * 700;
    int h = q / 100;
    int rm = q - h * 100;
    int r = rm / 10;
    int c = rm - r * 10;
    out[(size_t)(s0 + s_) * 700ull + q] = ha[s_ * 8 + h] * ro[s_ * 12 + r] * co[s_ * 12 + c];
  }
}

extern "C" void kernel_launch(void* const* d_in, const int* in_sizes, int n_in,
                              void* d_out, int out_size, void* d_ws, size_t ws_size,
                              hipStream_t stream) {
  const float* board = (const float*)d_in[0];
  const float* card  = (const float*)d_in[1];
  const float* c1w = (const float*)d_in[2];
  const float* c1b = (const float*)d_in[3];
  const float* c2w = (const float*)d_in[4];
  const float* c2b = (const float*)d_in[5];
  const float* f1w = (const float*)d_in[6];
  const float* f1b = (const float*)d_in[7];
  const float* f2w = (const float*)d_in[8];
  const float* f2b = (const float*)d_in[9];
  const float* r1w = (const float*)d_in[10];
  const float* r1b = (const float*)d_in[11];
  const float* r2w = (const float*)d_in[12];
  const float* r2b = (const float*)d_in[13];
  const float* r3w = (const float*)d_in[14];
  const float* r3b = (const float*)d_in[15];
  const float* co1w = (const float*)d_in[16];
  const float* co1b = (const float*)d_in[17];
  const float* co2w = (const float*)d_in[18];
  const float* co2b = (const float*)d_in[19];
  const float* co3w = (const float*)d_in[20];
  const float* co3b = (const float*)d_in[21];
  const float* h1w = (const float*)d_in[22];
  const float* h1b = (const float*)d_in[23];
  const float* h2w = (const float*)d_in[24];
  const float* h2b = (const float*)d_in[25];
  const float* h3w = (const float*)d_in[26];
  const float* h3b = (const float*)d_in[27];

  float* ws = (float*)d_ws;
  float* out = (float*)d_out;
  float* a1 = ws + OFF_A1;
  float* a2 = ws + OFF_A2;

  k_prep<<<32, 256, 0, stream>>>(f1w, f2w, r1w, r2w, r3w, co1w, co2w, co3w, h1w, h2w, h3w, ws);
  k_conv1<<<2048, 256, 0, stream>>>(board, c1w, c1b, a1);
  k_conv2<<<2048, 512, 0, stream>>>(a1, c2w, c2b, a2);
  k_fc<<<256, 256, 0, stream>>>(a2, card, ws, f1b, f2b,
                                r1b, r2b, r3b, co1b, co2b, co3b, h1b, h2b, h3b, out);
}